// Round 1
// baseline (838.754 us; speedup 1.0000x reference)
//
#include <hip/hip_runtime.h>
#include <hip/hip_bf16.h>
#include <math.h>

#define H_ 1024
#define D_ 2752
#define E_ 8
#define T_ 4096
#define MMAX_ 13312   /* max padded rows: 8*ceil + 4096 shared, 104 tiles of 128 */
#define MTILES_ 104

typedef __attribute__((ext_vector_type(8))) short s16x8;   // 8 bf16 in 4 VGPRs
typedef __attribute__((ext_vector_type(4))) float f32x4;

// ---------------- init: zero counters / row metadata ----------------
__global__ void k_init(int* __restrict__ count, int* __restrict__ perm,
                       float* __restrict__ wrow) {
    int i = blockIdx.x * 256 + threadIdx.x;
    if (i < E_) count[i] = 0;
    if (i < MMAX_) { perm[i] = 0; wrow[i] = 0.f; }
}

// ---------------- gate: fp32-exact logits, top-2, renormed weights ----------------
__global__ void k_gate(const float* __restrict__ x, const float* __restrict__ gw,
                       int* __restrict__ topk_e, float* __restrict__ topk_w,
                       int* __restrict__ count) {
    int t = blockIdx.x;
    int lane = threadIdx.x;   // 64 threads
    const float* xrow = x + (size_t)t * H_;
    float xr[16];
#pragma unroll
    for (int i = 0; i < 16; ++i) xr[i] = xrow[lane + i * 64];
    float lg[E_];
#pragma unroll
    for (int e = 0; e < E_; ++e) {
        const float* g = gw + (size_t)e * H_;
        float s = 0.f;
#pragma unroll
        for (int i = 0; i < 16; ++i) s += xr[i] * g[lane + i * 64];
        for (int o = 32; o > 0; o >>= 1) s += __shfl_down(s, o, 64);
        lg[e] = s;   // valid on lane 0
    }
    if (lane == 0) {
        int e0 = 0; float l0 = lg[0];
#pragma unroll
        for (int e = 1; e < E_; ++e) if (lg[e] > l0) { l0 = lg[e]; e0 = e; }
        int e1 = -1; float l1 = -1e30f;
#pragma unroll
        for (int e = 0; e < E_; ++e) if (e != e0 && lg[e] > l1) { l1 = lg[e]; e1 = e; }
        // p0/(p0+p1) with full-softmax denominators cancelling:
        float w0 = 1.f / (1.f + expf(l1 - l0));
        float w1 = 1.f - w0;
        topk_e[2 * t] = e0; topk_e[2 * t + 1] = e1;
        topk_w[2 * t] = w0; topk_w[2 * t + 1] = w1;
        atomicAdd(&count[e0], 1);
        atomicAdd(&count[e1], 1);
    }
}

// ---------------- scan: 128-aligned segment offsets ----------------
__global__ void k_scan(const int* __restrict__ count, int* __restrict__ off,
                       int* __restrict__ count2) {
    if (threadIdx.x == 0) {
        int o = 0; off[0] = 0;
        for (int e = 0; e < E_; ++e) { o += (count[e] + 127) & ~127; off[e + 1] = o; }
    }
    if (threadIdx.x < E_) count2[threadIdx.x] = 0;
}

// ---------------- scatter: token -> row (routed + shared segment) ----------------
__global__ void k_scatter(const int* __restrict__ topk_e, const float* __restrict__ topk_w,
                          const int* __restrict__ off, int* __restrict__ count2,
                          int* __restrict__ perm, float* __restrict__ wrow) {
    int i = blockIdx.x * 256 + threadIdx.x;
    if (i < 2 * T_) {
        int e = topk_e[i];
        int pos = atomicAdd(&count2[e], 1);
        int r = off[e] + pos;
        perm[r] = i >> 1;
        wrow[r] = topk_w[i];
    } else if (i < 3 * T_) {
        int t = i - 2 * T_;
        int r = off[E_] + t;     // shared-expert segment, weight 1
        perm[r] = t;
        wrow[r] = 1.f;
    }
}

// ---------------- gather: build Xg rows (bf16), zeros for pad rows ----------------
__global__ void k_gather(const float* __restrict__ x, const int* __restrict__ perm,
                         const float* __restrict__ wrow, __hip_bfloat16* __restrict__ Xg) {
    int r = blockIdx.x;
    int j = threadIdx.x;              // 128 threads, 8 elems each
    int t = perm[r];
    bool act = (wrow[r] != 0.f);
    const float* src = x + (size_t)t * H_;
    __hip_bfloat16* dst = Xg + (size_t)r * H_;
    int h = j * 8;
    float v[8];
#pragma unroll
    for (int i = 0; i < 8; ++i) v[i] = 0.f;
    if (act) {
        float4 a = *(const float4*)(src + h);
        float4 b = *(const float4*)(src + h + 4);
        v[0] = a.x; v[1] = a.y; v[2] = a.z; v[3] = a.w;
        v[4] = b.x; v[5] = b.y; v[6] = b.z; v[7] = b.w;
    }
    __hip_bfloat16 tmp[8];
#pragma unroll
    for (int i = 0; i < 8; ++i) tmp[i] = __float2bfloat16(v[i]);
    *(s16x8*)(dst + h) = *(const s16x8*)tmp;
}

// ---------------- transpose+convert: fp32 [R][C] -> bf16 [C][R] ----------------
__global__ void k_transpose(const float* __restrict__ src_, __hip_bfloat16* __restrict__ dst_,
                            int R, int C) {
    const float* src = src_ + (size_t)blockIdx.z * R * C;
    __hip_bfloat16* dst = dst_ + (size_t)blockIdx.z * R * C;
    __shared__ float tile[32][33];
    int c0 = blockIdx.x * 32, r0 = blockIdx.y * 32;
    int tx = threadIdx.x, ty = threadIdx.y;   // (32, 8)
#pragma unroll
    for (int i = 0; i < 4; ++i) {
        int rr = ty + i * 8;
        tile[rr][tx] = src[(size_t)(r0 + rr) * C + c0 + tx];
    }
    __syncthreads();
#pragma unroll
    for (int i = 0; i < 4; ++i) {
        int cc = ty + i * 8;
        dst[(size_t)(c0 + cc) * R + r0 + tx] = __float2bfloat16(tile[tx][cc]);
    }
}

// ---------------- GEMM1: hidden = silu(Xg*WgT^T) * (Xg*WuT^T), bf16 out ----------------
__global__ __launch_bounds__(256, 2) void k_gemm1(
    const unsigned short* __restrict__ Xg,
    const unsigned short* __restrict__ WgT,
    const unsigned short* __restrict__ WuT,
    __hip_bfloat16* __restrict__ hidden,
    const int* __restrict__ off) {
    __shared__ unsigned short As[128 * 32];
    __shared__ unsigned short Bgs[128 * 32];
    __shared__ unsigned short Bus[128 * 32];

    int row0 = blockIdx.y * 128;
    int off9[9];
#pragma unroll
    for (int i = 0; i < 9; ++i) off9[i] = off[i];
    int Mtot = off9[8] + T_;
    if (row0 >= Mtot) return;
    int e = 0;
#pragma unroll
    for (int i = 1; i < 9; ++i) e += (row0 >= off9[i]) ? 1 : 0;

    int n0 = blockIdx.x * 128;
    size_t wbase = (size_t)e * D_ * H_;
    const unsigned short* Bg = WgT + wbase;
    const unsigned short* Bu = WuT + wbase;

    int tid = threadIdx.x;
    int wave = tid >> 6, lane = tid & 63;
    int wm = wave >> 1, wn = wave & 1;
    int ml = lane & 15, q = lane >> 4;

    f32x4 accg[4][4], accu[4][4];
#pragma unroll
    for (int i = 0; i < 4; ++i)
#pragma unroll
        for (int j = 0; j < 4; ++j) { accg[i][j] = (f32x4)0.f; accu[i][j] = (f32x4)0.f; }

    // staging: 512 16B-chunks, 2 per thread. chunk c: row=c>>2, koff=(c&3)*8
    int ar0 = tid >> 2,          ak0 = (tid & 3) * 8;
    int ar1 = (tid + 256) >> 2,  ak1 = (tid & 3) * 8;   // (tid+256)&3 == tid&3
    int bn0 = n0 + ar0; if (bn0 > D_ - 1) bn0 = D_ - 1;
    int bn1 = n0 + ar1; if (bn1 > D_ - 1) bn1 = D_ - 1;

    for (int k0 = 0; k0 < H_; k0 += 32) {
        s16x8 a0 = *(const s16x8*)(Xg + (size_t)(row0 + ar0) * H_ + k0 + ak0);
        s16x8 a1 = *(const s16x8*)(Xg + (size_t)(row0 + ar1) * H_ + k0 + ak1);
        s16x8 g0 = *(const s16x8*)(Bg + (size_t)bn0 * H_ + k0 + ak0);
        s16x8 g1 = *(const s16x8*)(Bg + (size_t)bn1 * H_ + k0 + ak1);
        s16x8 u0 = *(const s16x8*)(Bu + (size_t)bn0 * H_ + k0 + ak0);
        s16x8 u1 = *(const s16x8*)(Bu + (size_t)bn1 * H_ + k0 + ak1);
        __syncthreads();   // previous iteration's LDS reads done
        *(s16x8*)(As  + ar0 * 32 + ak0) = a0;
        *(s16x8*)(As  + ar1 * 32 + ak1) = a1;
        *(s16x8*)(Bgs + ar0 * 32 + ak0) = g0;
        *(s16x8*)(Bgs + ar1 * 32 + ak1) = g1;
        *(s16x8*)(Bus + ar0 * 32 + ak0) = u0;
        *(s16x8*)(Bus + ar1 * 32 + ak1) = u1;
        __syncthreads();
        s16x8 af[4], bgf[4], buf[4];
#pragma unroll
        for (int i = 0; i < 4; ++i)
            af[i] = *(const s16x8*)(As + (wm * 64 + i * 16 + ml) * 32 + q * 8);
#pragma unroll
        for (int j = 0; j < 4; ++j) {
            bgf[j] = *(const s16x8*)(Bgs + (wn * 64 + j * 16 + ml) * 32 + q * 8);
            buf[j] = *(const s16x8*)(Bus + (wn * 64 + j * 16 + ml) * 32 + q * 8);
        }
#pragma unroll
        for (int i = 0; i < 4; ++i)
#pragma unroll
            for (int j = 0; j < 4; ++j) {
                accg[i][j] = __builtin_amdgcn_mfma_f32_16x16x32_bf16(af[i], bgf[j], accg[i][j], 0, 0, 0);
                accu[i][j] = __builtin_amdgcn_mfma_f32_16x16x32_bf16(af[i], buf[j], accu[i][j], 0, 0, 0);
            }
    }
    // epilogue: C/D layout col=lane&15, row=(lane>>4)*4+reg  [verified m89/m91]
    int mbase = row0 + wm * 64;
    int nbase = n0 + wn * 64;
#pragma unroll
    for (int i = 0; i < 4; ++i)
#pragma unroll
        for (int j = 0; j < 4; ++j) {
            int n = nbase + j * 16 + ml;
            if (n < D_) {
#pragma unroll
                for (int r = 0; r < 4; ++r) {
                    int m = mbase + i * 16 + q * 4 + r;
                    float g = accg[i][j][r], u = accu[i][j][r];
                    float hv = (g / (1.f + __expf(-g))) * u;   // silu(g)*u
                    hidden[(size_t)m * D_ + n] = __float2bfloat16(hv);
                }
            }
        }
}

// ---------------- GEMM2: out[perm[r]] += wrow[r] * (hidden * WdT^T) ----------------
__global__ __launch_bounds__(256, 2) void k_gemm2(
    const unsigned short* __restrict__ Hd,
    const unsigned short* __restrict__ WdT,
    const int* __restrict__ off, const int* __restrict__ perm,
    const float* __restrict__ wrow, float* __restrict__ out) {
    __shared__ unsigned short As[128 * 32];
    __shared__ unsigned short Bs[128 * 32];

    int row0 = blockIdx.y * 128;
    int off9[9];
#pragma unroll
    for (int i = 0; i < 9; ++i) off9[i] = off[i];
    int Mtot = off9[8] + T_;
    if (row0 >= Mtot) return;
    int e = 0;
#pragma unroll
    for (int i = 1; i < 9; ++i) e += (row0 >= off9[i]) ? 1 : 0;

    int n0 = blockIdx.x * 128;                       // N=1024, always in range
    const unsigned short* Bd = WdT + (size_t)e * H_ * D_;

    int tid = threadIdx.x;
    int wave = tid >> 6, lane = tid & 63;
    int wm = wave >> 1, wn = wave & 1;
    int ml = lane & 15, q = lane >> 4;

    f32x4 acc[4][4];
#pragma unroll
    for (int i = 0; i < 4; ++i)
#pragma unroll
        for (int j = 0; j < 4; ++j) acc[i][j] = (f32x4)0.f;

    int ar0 = tid >> 2,         ak0 = (tid & 3) * 8;
    int ar1 = (tid + 256) >> 2, ak1 = (tid & 3) * 8;

    for (int k0 = 0; k0 < D_; k0 += 32) {
        s16x8 a0 = *(const s16x8*)(Hd + (size_t)(row0 + ar0) * D_ + k0 + ak0);
        s16x8 a1 = *(const s16x8*)(Hd + (size_t)(row0 + ar1) * D_ + k0 + ak1);
        s16x8 b0 = *(const s16x8*)(Bd + (size_t)(n0 + ar0) * D_ + k0 + ak0);
        s16x8 b1 = *(const s16x8*)(Bd + (size_t)(n0 + ar1) * D_ + k0 + ak1);
        __syncthreads();
        *(s16x8*)(As + ar0 * 32 + ak0) = a0;
        *(s16x8*)(As + ar1 * 32 + ak1) = a1;
        *(s16x8*)(Bs + ar0 * 32 + ak0) = b0;
        *(s16x8*)(Bs + ar1 * 32 + ak1) = b1;
        __syncthreads();
        s16x8 af[4], bf[4];
#pragma unroll
        for (int i = 0; i < 4; ++i)
            af[i] = *(const s16x8*)(As + (wm * 64 + i * 16 + ml) * 32 + q * 8);
#pragma unroll
        for (int j = 0; j < 4; ++j)
            bf[j] = *(const s16x8*)(Bs + (wn * 64 + j * 16 + ml) * 32 + q * 8);
#pragma unroll
        for (int i = 0; i < 4; ++i)
#pragma unroll
            for (int j = 0; j < 4; ++j)
                acc[i][j] = __builtin_amdgcn_mfma_f32_16x16x32_bf16(af[i], bf[j], acc[i][j], 0, 0, 0);
    }
    int mbase = row0 + wm * 64;
    int nbase = n0 + wn * 64;
#pragma unroll
    for (int i = 0; i < 4; ++i)
#pragma unroll
        for (int r = 0; r < 4; ++r) {
            int m = mbase + i * 16 + q * 4 + r;
            float w = wrow[m];
            if (w != 0.f) {
                int t = perm[m];
#pragma unroll
                for (int j = 0; j < 4; ++j) {
                    int n = nbase + j * 16 + ml;
                    atomicAdd(&out[(size_t)t * H_ + n], w * acc[i][j][r]);
                }
            }
        }
}

// ---------------- launch ----------------
extern "C" void kernel_launch(void* const* d_in, const int* in_sizes, int n_in,
                              void* d_out, int out_size, void* d_ws, size_t ws_size,
                              hipStream_t stream) {
    const float* x       = (const float*)d_in[0];
    const float* gw      = (const float*)d_in[1];
    const float* we_gate = (const float*)d_in[2];
    const float* we_up   = (const float*)d_in[3];
    const float* we_down = (const float*)d_in[4];
    const float* sw_gate = (const float*)d_in[5];
    const float* sw_up   = (const float*)d_in[6];
    const float* sw_down = (const float*)d_in[7];

    char* ws = (char*)d_ws;
    size_t o = 0;
    auto alloc = [&](size_t b) -> void* {
        void* p = ws + o;
        o += (b + 255) & ~(size_t)255;
        return p;
    };
    int*   count  = (int*)alloc(E_ * 4);
    int*   count2 = (int*)alloc(E_ * 4);
    int*   off    = (int*)alloc(16 * 4);
    int*   topk_e = (int*)alloc(2 * T_ * 4);
    float* topk_w = (float*)alloc(2 * T_ * 4);
    int*   perm   = (int*)alloc(MMAX_ * 4);
    float* wrow   = (float*)alloc(MMAX_ * 4);
    __hip_bfloat16* Xg  = (__hip_bfloat16*)alloc((size_t)MMAX_ * H_ * 2);
    __hip_bfloat16* WgT = (__hip_bfloat16*)alloc((size_t)(E_ + 1) * D_ * H_ * 2);
    __hip_bfloat16* WuT = (__hip_bfloat16*)alloc((size_t)(E_ + 1) * D_ * H_ * 2);
    __hip_bfloat16* WdT = (__hip_bfloat16*)alloc((size_t)(E_ + 1) * H_ * D_ * 2);
    __hip_bfloat16* hidden = (__hip_bfloat16*)alloc((size_t)MMAX_ * D_ * 2);

    // routing
    k_init<<<(MMAX_ + 255) / 256, 256, 0, stream>>>(count, perm, wrow);
    k_gate<<<T_, 64, 0, stream>>>(x, gw, topk_e, topk_w, count);
    k_scan<<<1, 64, 0, stream>>>(count, off, count2);
    k_scatter<<<(3 * T_ + 255) / 256, 256, 0, stream>>>(topk_e, topk_w, off, count2, perm, wrow);
    k_gather<<<MMAX_, 128, 0, stream>>>(x, perm, wrow, Xg);

    // weight transpose+convert: experts in slots 0..7, shared in slot 8
    size_t msz = (size_t)D_ * H_;
    k_transpose<<<dim3(D_ / 32, H_ / 32, E_), dim3(32, 8), 0, stream>>>(we_gate, WgT, H_, D_);
    k_transpose<<<dim3(D_ / 32, H_ / 32, 1), dim3(32, 8), 0, stream>>>(sw_gate, WgT + E_ * msz, H_, D_);
    k_transpose<<<dim3(D_ / 32, H_ / 32, E_), dim3(32, 8), 0, stream>>>(we_up, WuT, H_, D_);
    k_transpose<<<dim3(D_ / 32, H_ / 32, 1), dim3(32, 8), 0, stream>>>(sw_up, WuT + E_ * msz, H_, D_);
    k_transpose<<<dim3(H_ / 32, D_ / 32, E_), dim3(32, 8), 0, stream>>>(we_down, WdT, D_, H_);
    k_transpose<<<dim3(H_ / 32, D_ / 32, 1), dim3(32, 8), 0, stream>>>(sw_down, WdT + E_ * msz, D_, H_);

    // GEMM1: fused gate+up+silu -> hidden (bf16)
    k_gemm1<<<dim3((D_ + 127) / 128, MTILES_), 256, 0, stream>>>(
        (const unsigned short*)Xg, (const unsigned short*)WgT, (const unsigned short*)WuT,
        hidden, off);

    // GEMM2: down-proj with weighted scatter-add into zeroed output
    hipMemsetAsync(d_out, 0, (size_t)out_size * sizeof(float), stream);
    k_gemm2<<<dim3(H_ / 128, MTILES_), 256, 0, stream>>>(
        (const unsigned short*)hidden, (const unsigned short*)WdT,
        off, perm, wrow, (float*)d_out);
}

// Round 2
// 825.662 us; speedup vs baseline: 1.0159x; 1.0159x over previous
//
#include <hip/hip_runtime.h>
#include <hip/hip_bf16.h>
#include <math.h>

#define H_ 1024
#define D_ 2752
#define E_ 8
#define T_ 4096
#define MMAX_ 13312   /* max padded rows: 8 segs 128-aligned + 4096 shared */
#define MTILES_ 104

typedef __attribute__((ext_vector_type(8))) short s16x8;   // 8 bf16 in 4 VGPRs
typedef __attribute__((ext_vector_type(4))) float f32x4;

// async global->LDS, 16B per lane, LDS dest = wave-uniform base + lane*16
typedef __attribute__((address_space(3))) unsigned int lds_u32;
typedef const __attribute__((address_space(1))) unsigned int gbl_u32;
__device__ __forceinline__ void gload_lds16(const void* g, void* l) {
    __builtin_amdgcn_global_load_lds((gbl_u32*)g, (lds_u32*)l, 16, 0, 0);
}

// ---------------- init: zero counters / row metadata ----------------
__global__ void k_init(int* __restrict__ count, int* __restrict__ perm,
                       float* __restrict__ wrow) {
    int i = blockIdx.x * 256 + threadIdx.x;
    if (i < E_) count[i] = 0;
    if (i < MMAX_) { perm[i] = 0; wrow[i] = 0.f; }
}

// ---------------- gate: fp32-exact logits, top-2, renormed weights ----------------
__global__ void k_gate(const float* __restrict__ x, const float* __restrict__ gw,
                       int* __restrict__ topk_e, float* __restrict__ topk_w,
                       int* __restrict__ count) {
    int t = blockIdx.x;
    int lane = threadIdx.x;   // 64 threads
    const float* xrow = x + (size_t)t * H_;
    float xr[16];
#pragma unroll
    for (int i = 0; i < 16; ++i) xr[i] = xrow[lane + i * 64];
    float lg[E_];
#pragma unroll
    for (int e = 0; e < E_; ++e) {
        const float* g = gw + (size_t)e * H_;
        float s = 0.f;
#pragma unroll
        for (int i = 0; i < 16; ++i) s += xr[i] * g[lane + i * 64];
        for (int o = 32; o > 0; o >>= 1) s += __shfl_down(s, o, 64);
        lg[e] = s;   // valid on lane 0
    }
    if (lane == 0) {
        int e0 = 0; float l0 = lg[0];
#pragma unroll
        for (int e = 1; e < E_; ++e) if (lg[e] > l0) { l0 = lg[e]; e0 = e; }
        int e1 = -1; float l1 = -1e30f;
#pragma unroll
        for (int e = 0; e < E_; ++e) if (e != e0 && lg[e] > l1) { l1 = lg[e]; e1 = e; }
        float w0 = 1.f / (1.f + expf(l1 - l0));   // softmax denom cancels in renorm
        float w1 = 1.f - w0;
        topk_e[2 * t] = e0; topk_e[2 * t + 1] = e1;
        topk_w[2 * t] = w0; topk_w[2 * t + 1] = w1;
        atomicAdd(&count[e0], 1);
        atomicAdd(&count[e1], 1);
    }
}

// ---------------- scan: 128-aligned segment offsets ----------------
__global__ void k_scan(const int* __restrict__ count, int* __restrict__ off,
                       int* __restrict__ count2) {
    if (threadIdx.x == 0) {
        int o = 0; off[0] = 0;
        for (int e = 0; e < E_; ++e) { o += (count[e] + 127) & ~127; off[e + 1] = o; }
    }
    if (threadIdx.x < E_) count2[threadIdx.x] = 0;
}

// ---------------- scatter: token -> row; also record token's row ids ----------------
__global__ void k_scatter(const int* __restrict__ topk_e, const float* __restrict__ topk_w,
                          const int* __restrict__ off, int* __restrict__ count2,
                          int* __restrict__ perm, float* __restrict__ wrow,
                          int* __restrict__ tok2row) {
    int i = blockIdx.x * 256 + threadIdx.x;
    if (i < 2 * T_) {
        int e = topk_e[i];
        int pos = atomicAdd(&count2[e], 1);
        int r = off[e] + pos;
        perm[r] = i >> 1;
        wrow[r] = topk_w[i];
        tok2row[i] = r;
    } else if (i < 3 * T_) {
        int t = i - 2 * T_;
        int r = off[E_] + t;     // shared-expert segment
        perm[r] = t;
        wrow[r] = 1.f;
    }
}

// ---------------- gather: build Xg rows (bf16), zeros for pad rows ----------------
__global__ void k_gather(const float* __restrict__ x, const int* __restrict__ perm,
                         const float* __restrict__ wrow, __hip_bfloat16* __restrict__ Xg) {
    int r = blockIdx.x;
    int j = threadIdx.x;              // 128 threads, 8 elems each
    int t = perm[r];
    bool act = (wrow[r] != 0.f);
    const float* src = x + (size_t)t * H_;
    __hip_bfloat16* dst = Xg + (size_t)r * H_;
    int h = j * 8;
    float v[8];
#pragma unroll
    for (int i = 0; i < 8; ++i) v[i] = 0.f;
    if (act) {
        float4 a = *(const float4*)(src + h);
        float4 b = *(const float4*)(src + h + 4);
        v[0] = a.x; v[1] = a.y; v[2] = a.z; v[3] = a.w;
        v[4] = b.x; v[5] = b.y; v[6] = b.z; v[7] = b.w;
    }
    __hip_bfloat16 tmp[8];
#pragma unroll
    for (int i = 0; i < 8; ++i) tmp[i] = __float2bfloat16(v[i]);
    *(s16x8*)(dst + h) = *(const s16x8*)tmp;
}

// ---------------- transpose+convert: fp32 [R][C] -> bf16 [C][R], 64x64 tiles ----------------
__global__ void k_transpose(const float* __restrict__ src_, __hip_bfloat16* __restrict__ dst_,
                            int R, int C) {
    const float* src = src_ + (size_t)blockIdx.z * R * C;
    __hip_bfloat16* dst = dst_ + (size_t)blockIdx.z * R * C;
    __shared__ __hip_bfloat16 tile[64][68];   // 68: 8B-aligned rows, conflict break
    int c0 = blockIdx.x * 64, r0 = blockIdx.y * 64;
    int tid = threadIdx.x;                     // 256
    int rsub = tid >> 4;                       // 0..15
    int csub = (tid & 15) * 4;                 // 0..60
#pragma unroll
    for (int i = 0; i < 4; ++i) {
        int r = rsub + i * 16;
        float4 v = *(const float4*)(src + (size_t)(r0 + r) * C + c0 + csub);
        tile[csub + 0][r] = __float2bfloat16(v.x);
        tile[csub + 1][r] = __float2bfloat16(v.y);
        tile[csub + 2][r] = __float2bfloat16(v.z);
        tile[csub + 3][r] = __float2bfloat16(v.w);
    }
    __syncthreads();
    int cs2 = tid >> 4;
    int rs2 = (tid & 15) * 4;
#pragma unroll
    for (int i = 0; i < 4; ++i) {
        int cc = cs2 + i * 16;
        short4 o = *(const short4*)&tile[cc][rs2];
        *(short4*)((unsigned short*)dst + (size_t)(c0 + cc) * R + r0 + rs2) = o;
    }
}

// ---------------- GEMM1: hidden = silu(Xg*WgT^T) * (Xg*WuT^T), bf16 out ----------------
__global__ __launch_bounds__(256, 2) void k_gemm1(
    const unsigned short* __restrict__ Xg,
    const unsigned short* __restrict__ WgT,
    const unsigned short* __restrict__ WuT,
    __hip_bfloat16* __restrict__ hidden,
    const int* __restrict__ off) {
    __shared__ unsigned short As[128 * 32];
    __shared__ unsigned short Bgs[128 * 32];
    __shared__ unsigned short Bus[128 * 32];

    int row0 = blockIdx.y * 128;
    int off9[9];
#pragma unroll
    for (int i = 0; i < 9; ++i) off9[i] = off[i];
    int Mtot = off9[8] + T_;                 // 128-aligned
    if (row0 >= Mtot) return;
    int e = 0;
#pragma unroll
    for (int i = 1; i < 9; ++i) e += (row0 >= off9[i]) ? 1 : 0;

    int n0 = blockIdx.x * 128;
    size_t wbase = (size_t)e * D_ * H_;
    const unsigned short* Bg = WgT + wbase;
    const unsigned short* Bu = WuT + wbase;

    int tid = threadIdx.x;
    int wave = tid >> 6, lane = tid & 63;
    int wm = wave >> 1, wn = wave & 1;
    int ml = lane & 15, q = lane >> 4;

    f32x4 accg[4][4], accu[4][4];
#pragma unroll
    for (int i = 0; i < 4; ++i)
#pragma unroll
        for (int j = 0; j < 4; ++j) { accg[i][j] = (f32x4)0.f; accu[i][j] = (f32x4)0.f; }

    // 24 direct-to-LDS issues per k-step (3 bufs x 8), 6 per wave.
    // issue q: buf=q>>3, s=q&7; lane l -> row s*16+(l>>2), kchunk (l&3)*8;
    // LDS dest = buf_base + s*1024B + lane*16B  == packed [row][32k] layout.
    const unsigned short* gsrc[6];
    unsigned short* lbase[6];
#pragma unroll
    for (int i = 0; i < 6; ++i) {
        int qq = wave * 6 + i;
        int buf = qq >> 3, s = qq & 7;
        int rr = s * 16 + (lane >> 2);
        int cc = (lane & 3) * 8;
        unsigned short* lb = (buf == 0 ? As : buf == 1 ? Bgs : Bus) + s * 512;
        const unsigned short* g;
        if (buf == 0) {
            g = Xg + (size_t)(row0 + rr) * H_ + cc;
        } else {
            int bn = n0 + rr; if (bn > D_ - 1) bn = D_ - 1;   // dup-load tail, masked in epilogue
            g = (buf == 1 ? Bg : Bu) + (size_t)bn * H_ + cc;
        }
        gsrc[i] = g; lbase[i] = lb;
    }

    for (int k0 = 0; k0 < H_; k0 += 32) {
        __syncthreads();                       // prior LDS reads done
#pragma unroll
        for (int i = 0; i < 6; ++i)
            gload_lds16(gsrc[i] + k0, lbase[i]);
        __syncthreads();                       // drains vmcnt; LDS ready
        s16x8 af[4], bgf[4], buf2[4];
#pragma unroll
        for (int i = 0; i < 4; ++i)
            af[i] = *(const s16x8*)(As + (wm * 64 + i * 16 + ml) * 32 + q * 8);
#pragma unroll
        for (int j = 0; j < 4; ++j) {
            bgf[j]  = *(const s16x8*)(Bgs + (wn * 64 + j * 16 + ml) * 32 + q * 8);
            buf2[j] = *(const s16x8*)(Bus + (wn * 64 + j * 16 + ml) * 32 + q * 8);
        }
#pragma unroll
        for (int i = 0; i < 4; ++i)
#pragma unroll
            for (int j = 0; j < 4; ++j) {
                accg[i][j] = __builtin_amdgcn_mfma_f32_16x16x32_bf16(af[i], bgf[j],  accg[i][j], 0, 0, 0);
                accu[i][j] = __builtin_amdgcn_mfma_f32_16x16x32_bf16(af[i], buf2[j], accu[i][j], 0, 0, 0);
            }
    }
    // epilogue: C/D layout col=lane&15, row=(lane>>4)*4+reg  [m89/m91]
    int mbase = row0 + wm * 64;
    int nbase = n0 + wn * 64;
#pragma unroll
    for (int i = 0; i < 4; ++i)
#pragma unroll
        for (int j = 0; j < 4; ++j) {
            int n = nbase + j * 16 + ml;
            if (n < D_) {
#pragma unroll
                for (int r = 0; r < 4; ++r) {
                    int m = mbase + i * 16 + q * 4 + r;
                    float g = accg[i][j][r], u = accu[i][j][r];
                    float hv = (g / (1.f + __expf(-g))) * u;   // silu(g)*u
                    hidden[(size_t)m * D_ + n] = __float2bfloat16(hv);
                }
            }
        }
}

// ---------------- GEMM2: eo[r] = hidden[r] * WdT^T  (unweighted, plain stores) ----------------
__global__ __launch_bounds__(256, 2) void k_gemm2(
    const unsigned short* __restrict__ Hd,
    const unsigned short* __restrict__ WdT,
    const int* __restrict__ off,
    float* __restrict__ eo) {
    __shared__ unsigned short As[128 * 32];
    __shared__ unsigned short Bs[128 * 32];

    int row0 = blockIdx.y * 128;
    int off9[9];
#pragma unroll
    for (int i = 0; i < 9; ++i) off9[i] = off[i];
    int Mtot = off9[8] + T_;
    if (row0 >= Mtot) return;
    int e = 0;
#pragma unroll
    for (int i = 1; i < 9; ++i) e += (row0 >= off9[i]) ? 1 : 0;

    int n0 = blockIdx.x * 128;                      // N=1024, exact
    const unsigned short* Bd = WdT + (size_t)e * H_ * D_;

    int tid = threadIdx.x;
    int wave = tid >> 6, lane = tid & 63;
    int wm = wave >> 1, wn = wave & 1;
    int ml = lane & 15, q = lane >> 4;

    f32x4 acc[4][4];
#pragma unroll
    for (int i = 0; i < 4; ++i)
#pragma unroll
        for (int j = 0; j < 4; ++j) acc[i][j] = (f32x4)0.f;

    // 16 issues per k-step (2 bufs x 8), 4 per wave
    const unsigned short* gsrc[4];
    unsigned short* lbase[4];
#pragma unroll
    for (int i = 0; i < 4; ++i) {
        int qq = wave * 4 + i;
        int buf = qq >> 3, s = qq & 7;
        int rr = s * 16 + (lane >> 2);
        int cc = (lane & 3) * 8;
        unsigned short* lb = (buf == 0 ? As : Bs) + s * 512;
        const unsigned short* g = (buf == 0)
            ? Hd + (size_t)(row0 + rr) * D_ + cc
            : Bd + (size_t)(n0 + rr) * D_ + cc;
        gsrc[i] = g; lbase[i] = lb;
    }

    for (int k0 = 0; k0 < D_; k0 += 32) {
        __syncthreads();
#pragma unroll
        for (int i = 0; i < 4; ++i)
            gload_lds16(gsrc[i] + k0, lbase[i]);
        __syncthreads();
        s16x8 af[4], bf[4];
#pragma unroll
        for (int i = 0; i < 4; ++i)
            af[i] = *(const s16x8*)(As + (wm * 64 + i * 16 + ml) * 32 + q * 8);
#pragma unroll
        for (int j = 0; j < 4; ++j)
            bf[j] = *(const s16x8*)(Bs + (wn * 64 + j * 16 + ml) * 32 + q * 8);
#pragma unroll
        for (int i = 0; i < 4; ++i)
#pragma unroll
            for (int j = 0; j < 4; ++j)
                acc[i][j] = __builtin_amdgcn_mfma_f32_16x16x32_bf16(af[i], bf[j], acc[i][j], 0, 0, 0);
    }
    int mbase = row0 + wm * 64;
    int nbase = n0 + wn * 64;
#pragma unroll
    for (int i = 0; i < 4; ++i)
#pragma unroll
        for (int r = 0; r < 4; ++r) {
            int m = mbase + i * 16 + q * 4 + r;
#pragma unroll
            for (int j = 0; j < 4; ++j) {
                int n = nbase + j * 16 + ml;
                eo[(size_t)m * H_ + n] = acc[i][j][r];
            }
        }
}

// ---------------- combine: out[t] = w0*eo[r0] + w1*eo[r1] + eo[rshared] ----------------
__global__ void k_combine(const float* __restrict__ eo, const int* __restrict__ tok2row,
                          const int* __restrict__ off, const float* __restrict__ topk_w,
                          float* __restrict__ out) {
    int t = blockIdx.x;
    int j = threadIdx.x * 4;                  // H = 256*4
    int r0 = tok2row[2 * t], r1 = tok2row[2 * t + 1];
    int rs = off[E_] + t;
    float w0 = topk_w[2 * t], w1 = topk_w[2 * t + 1];
    float4 a = *(const float4*)(eo + (size_t)r0 * H_ + j);
    float4 b = *(const float4*)(eo + (size_t)r1 * H_ + j);
    float4 c = *(const float4*)(eo + (size_t)rs * H_ + j);
    float4 o;
    o.x = w0 * a.x + w1 * b.x + c.x;
    o.y = w0 * a.y + w1 * b.y + c.y;
    o.z = w0 * a.z + w1 * b.z + c.z;
    o.w = w0 * a.w + w1 * b.w + c.w;
    *(float4*)(out + (size_t)t * H_ + j) = o;
}

// ---------------- launch ----------------
extern "C" void kernel_launch(void* const* d_in, const int* in_sizes, int n_in,
                              void* d_out, int out_size, void* d_ws, size_t ws_size,
                              hipStream_t stream) {
    const float* x       = (const float*)d_in[0];
    const float* gw      = (const float*)d_in[1];
    const float* we_gate = (const float*)d_in[2];
    const float* we_up   = (const float*)d_in[3];
    const float* we_down = (const float*)d_in[4];
    const float* sw_gate = (const float*)d_in[5];
    const float* sw_up   = (const float*)d_in[6];
    const float* sw_down = (const float*)d_in[7];

    char* ws = (char*)d_ws;
    size_t o = 0;
    auto alloc = [&](size_t b) -> void* {
        void* p = ws + o;
        o += (b + 255) & ~(size_t)255;
        return p;
    };
    int*   count   = (int*)alloc(E_ * 4);
    int*   count2  = (int*)alloc(E_ * 4);
    int*   off     = (int*)alloc(16 * 4);
    int*   topk_e  = (int*)alloc(2 * T_ * 4);
    float* topk_w  = (float*)alloc(2 * T_ * 4);
    int*   perm    = (int*)alloc(MMAX_ * 4);
    float* wrow    = (float*)alloc(MMAX_ * 4);
    int*   tok2row = (int*)alloc(2 * T_ * 4);
    __hip_bfloat16* Xg  = (__hip_bfloat16*)alloc((size_t)MMAX_ * H_ * 2);
    __hip_bfloat16* WgT = (__hip_bfloat16*)alloc((size_t)(E_ + 1) * D_ * H_ * 2);
    __hip_bfloat16* WuT = (__hip_bfloat16*)alloc((size_t)(E_ + 1) * D_ * H_ * 2);
    __hip_bfloat16* WdT = (__hip_bfloat16*)alloc((size_t)(E_ + 1) * H_ * D_ * 2);
    __hip_bfloat16* hidden = (__hip_bfloat16*)alloc((size_t)MMAX_ * D_ * 2);
    // eo (fp32, 54.5 MB) aliases WgT+WuT (101 MB), both dead after GEMM1
    float* eo = (float*)WgT;

    // routing
    k_init<<<(MMAX_ + 255) / 256, 256, 0, stream>>>(count, perm, wrow);
    k_gate<<<T_, 64, 0, stream>>>(x, gw, topk_e, topk_w, count);
    k_scan<<<1, 64, 0, stream>>>(count, off, count2);
    k_scatter<<<(3 * T_ + 255) / 256, 256, 0, stream>>>(topk_e, topk_w, off, count2,
                                                        perm, wrow, tok2row);
    k_gather<<<MMAX_, 128, 0, stream>>>(x, perm, wrow, Xg);

    // weight transpose+convert: experts in slots 0..7, shared in slot 8
    size_t msz = (size_t)D_ * H_;
    k_transpose<<<dim3(D_ / 64, H_ / 64, E_), 256, 0, stream>>>(we_gate, WgT, H_, D_);
    k_transpose<<<dim3(D_ / 64, H_ / 64, 1), 256, 0, stream>>>(sw_gate, WgT + E_ * msz, H_, D_);
    k_transpose<<<dim3(D_ / 64, H_ / 64, E_), 256, 0, stream>>>(we_up, WuT, H_, D_);
    k_transpose<<<dim3(D_ / 64, H_ / 64, 1), 256, 0, stream>>>(sw_up, WuT + E_ * msz, H_, D_);
    k_transpose<<<dim3(H_ / 64, D_ / 64, E_), 256, 0, stream>>>(we_down, WdT, D_, H_);
    k_transpose<<<dim3(H_ / 64, D_ / 64, 1), 256, 0, stream>>>(sw_down, WdT + E_ * msz, D_, H_);

    // GEMM1: fused gate+up+silu -> hidden (bf16)
    k_gemm1<<<dim3((D_ + 127) / 128, MTILES_), 256, 0, stream>>>(
        (const unsigned short*)Xg, (const unsigned short*)WgT, (const unsigned short*)WuT,
        hidden, off);

    // GEMM2: down-proj -> eo rows (fp32, unweighted)
    k_gemm2<<<dim3(H_ / 128, MTILES_), 256, 0, stream>>>(
        (const unsigned short*)hidden, (const unsigned short*)WdT, off, eo);

    // combine: weighted sum of the token's 3 rows
    k_combine<<<T_, 256, 0, stream>>>(eo, tok2row, off, topk_w, (float*)d_out);
}

// Round 3
// 785.526 us; speedup vs baseline: 1.0678x; 1.0511x over previous
//
#include <hip/hip_runtime.h>
#include <hip/hip_bf16.h>
#include <math.h>

#define H_ 1024
#define D_ 2752
#define E_ 8
#define T_ 4096
#define MMAX_ 13312   /* max padded rows: 8 segs 128-aligned + 4096 shared */
#define MTILES_ 104

typedef __attribute__((ext_vector_type(8))) short s16x8;   // 8 bf16 in 4 VGPRs
typedef __attribute__((ext_vector_type(4))) float f32x4;

// async global->LDS, 16B per lane, LDS dest = wave-uniform base + lane*16
typedef __attribute__((address_space(3))) unsigned int lds_u32;
typedef const __attribute__((address_space(1))) unsigned int gbl_u32;
__device__ __forceinline__ void gload_lds16(const void* g, void* l) {
    __builtin_amdgcn_global_load_lds((gbl_u32*)g, (lds_u32*)l, 16, 0, 0);
}

__device__ __forceinline__ float bf2f(short us) {
    unsigned int u = ((unsigned int)(unsigned short)us) << 16;
    return __uint_as_float(u);
}

// ---------------- init: zero counters / row metadata ----------------
__global__ void k_init(int* __restrict__ count, int* __restrict__ perm,
                       float* __restrict__ wrow) {
    int i = blockIdx.x * 256 + threadIdx.x;
    if (i < E_) count[i] = 0;
    if (i < MMAX_) { perm[i] = 0; wrow[i] = 0.f; }
}

// ---------------- gate: fp32-exact logits, top-2, renormed weights ----------------
__global__ void k_gate(const float* __restrict__ x, const float* __restrict__ gw,
                       int* __restrict__ topk_e, float* __restrict__ topk_w,
                       int* __restrict__ count) {
    int t = blockIdx.x;
    int lane = threadIdx.x;   // 64 threads
    const float* xrow = x + (size_t)t * H_;
    float xr[16];
#pragma unroll
    for (int i = 0; i < 16; ++i) xr[i] = xrow[lane + i * 64];
    float lg[E_];
#pragma unroll
    for (int e = 0; e < E_; ++e) {
        const float* g = gw + (size_t)e * H_;
        float s = 0.f;
#pragma unroll
        for (int i = 0; i < 16; ++i) s += xr[i] * g[lane + i * 64];
        for (int o = 32; o > 0; o >>= 1) s += __shfl_down(s, o, 64);
        lg[e] = s;   // valid on lane 0
    }
    if (lane == 0) {
        int e0 = 0; float l0 = lg[0];
#pragma unroll
        for (int e = 1; e < E_; ++e) if (lg[e] > l0) { l0 = lg[e]; e0 = e; }
        int e1 = -1; float l1 = -1e30f;
#pragma unroll
        for (int e = 0; e < E_; ++e) if (e != e0 && lg[e] > l1) { l1 = lg[e]; e1 = e; }
        float w0 = 1.f / (1.f + expf(l1 - l0));   // softmax denom cancels in renorm
        float w1 = 1.f - w0;
        topk_e[2 * t] = e0; topk_e[2 * t + 1] = e1;
        topk_w[2 * t] = w0; topk_w[2 * t + 1] = w1;
        atomicAdd(&count[e0], 1);
        atomicAdd(&count[e1], 1);
    }
}

// ---------------- scan: 128-aligned segment offsets ----------------
__global__ void k_scan(const int* __restrict__ count, int* __restrict__ off,
                       int* __restrict__ count2) {
    if (threadIdx.x == 0) {
        int o = 0; off[0] = 0;
        for (int e = 0; e < E_; ++e) { o += (count[e] + 127) & ~127; off[e + 1] = o; }
    }
    if (threadIdx.x < E_) count2[threadIdx.x] = 0;
}

// ---------------- scatter: token -> row; also record token's row ids ----------------
__global__ void k_scatter(const int* __restrict__ topk_e, const float* __restrict__ topk_w,
                          const int* __restrict__ off, int* __restrict__ count2,
                          int* __restrict__ perm, float* __restrict__ wrow,
                          int* __restrict__ tok2row) {
    int i = blockIdx.x * 256 + threadIdx.x;
    if (i < 2 * T_) {
        int e = topk_e[i];
        int pos = atomicAdd(&count2[e], 1);
        int r = off[e] + pos;
        perm[r] = i >> 1;
        wrow[r] = topk_w[i];
        tok2row[i] = r;
    } else if (i < 3 * T_) {
        int t = i - 2 * T_;
        int r = off[E_] + t;     // shared-expert segment
        perm[r] = t;
        wrow[r] = 1.f;
    }
}

// ---------------- gather: build Xg rows (bf16), zeros for pad rows ----------------
__global__ void k_gather(const float* __restrict__ x, const int* __restrict__ perm,
                         const float* __restrict__ wrow, __hip_bfloat16* __restrict__ Xg) {
    int r = blockIdx.x;
    int j = threadIdx.x;              // 128 threads, 8 elems each
    int t = perm[r];
    bool act = (wrow[r] != 0.f);
    const float* src = x + (size_t)t * H_;
    __hip_bfloat16* dst = Xg + (size_t)r * H_;
    int h = j * 8;
    float v[8];
#pragma unroll
    for (int i = 0; i < 8; ++i) v[i] = 0.f;
    if (act) {
        float4 a = *(const float4*)(src + h);
        float4 b = *(const float4*)(src + h + 4);
        v[0] = a.x; v[1] = a.y; v[2] = a.z; v[3] = a.w;
        v[4] = b.x; v[5] = b.y; v[6] = b.z; v[7] = b.w;
    }
    __hip_bfloat16 tmp[8];
#pragma unroll
    for (int i = 0; i < 8; ++i) tmp[i] = __float2bfloat16(v[i]);
    *(s16x8*)(dst + h) = *(const s16x8*)tmp;
}

// ---------------- transpose+convert: fp32 [R][C] -> bf16 [C][R], 64x64 tiles ----------------
__global__ void k_transpose(const float* __restrict__ src_, __hip_bfloat16* __restrict__ dst_,
                            int R, int C) {
    const float* src = src_ + (size_t)blockIdx.z * R * C;
    __hip_bfloat16* dst = dst_ + (size_t)blockIdx.z * R * C;
    __shared__ __hip_bfloat16 tile[64][68];   // 68: 8B-aligned rows, conflict break
    int c0 = blockIdx.x * 64, r0 = blockIdx.y * 64;
    int tid = threadIdx.x;                     // 256
    int rsub = tid >> 4;                       // 0..15
    int csub = (tid & 15) * 4;                 // 0..60
#pragma unroll
    for (int i = 0; i < 4; ++i) {
        int r = rsub + i * 16;
        float4 v = *(const float4*)(src + (size_t)(r0 + r) * C + c0 + csub);
        tile[csub + 0][r] = __float2bfloat16(v.x);
        tile[csub + 1][r] = __float2bfloat16(v.y);
        tile[csub + 2][r] = __float2bfloat16(v.z);
        tile[csub + 3][r] = __float2bfloat16(v.w);
    }
    __syncthreads();
    int cs2 = tid >> 4;
    int rs2 = (tid & 15) * 4;
#pragma unroll
    for (int i = 0; i < 4; ++i) {
        int cc = cs2 + i * 16;
        short4 o = *(const short4*)&tile[cc][rs2];
        *(short4*)((unsigned short*)dst + (size_t)(c0 + cc) * R + r0 + rs2) = o;
    }
}

// Bank-swizzle: chunk (tile-row R, k-chunk q of 8 bf16) lives at ushort offset
// R*32 + ((q + (R>>1)) & 3) * 8 within its staging buffer. Staging lane l of
// issue s holds slot l&3 of row s*16 + (l>>2)  ->  global chunk
// c = ((l&3) - (row>>1)) & 3. 8 consecutive lanes of a ds_read_b128 then
// cover all 8 bank-quads (conflict-free).

// ---------------- GEMM1: hidden = silu(Xg*WgT^T) * (Xg*WuT^T), bf16 out ----------------
__global__ __launch_bounds__(256, 2) void k_gemm1(
    const unsigned short* __restrict__ Xg,
    const unsigned short* __restrict__ WgT,
    const unsigned short* __restrict__ WuT,
    __hip_bfloat16* __restrict__ hidden,
    const int* __restrict__ off) {
    __shared__ unsigned short lds[2][3][4096];   // 2 sets x {A,Bg,Bu} x 8KB

    int row0 = blockIdx.y * 128;
    int off9[9];
#pragma unroll
    for (int i = 0; i < 9; ++i) off9[i] = off[i];
    int Mtot = off9[8] + T_;                 // 128-aligned
    if (row0 >= Mtot) return;
    int e = 0;
#pragma unroll
    for (int i = 1; i < 9; ++i) e += (row0 >= off9[i]) ? 1 : 0;

    int n0 = blockIdx.x * 128;
    size_t wbase = (size_t)e * D_ * H_;
    const unsigned short* Bg = WgT + wbase;
    const unsigned short* Bu = WuT + wbase;

    int tid = threadIdx.x;
    int wave = tid >> 6, lane = tid & 63;
    int wm = wave >> 1, wn = wave & 1;
    int ml = lane & 15, q = lane >> 4;
    int sw = ((q + (ml >> 1)) & 3) * 8;     // read-side swizzle (uniform in i/j)

    f32x4 accg[4][4], accu[4][4];
#pragma unroll
    for (int i = 0; i < 4; ++i)
#pragma unroll
        for (int j = 0; j < 4; ++j) { accg[i][j] = (f32x4)0.f; accu[i][j] = (f32x4)0.f; }

    // 24 direct-to-LDS issues per k-step (3 bufs x 8), 6 per wave
    const unsigned short* gsrc[6];
    unsigned short* lbase[6];
#pragma unroll
    for (int i = 0; i < 6; ++i) {
        int qq = wave * 6 + i;
        int buf = qq >> 3, s = qq & 7;
        int r = s * 16 + (lane >> 2);                    // tile-local row
        int c = ((lane & 3) - (r >> 1)) & 3;             // swizzled k-chunk
        lbase[i] = &lds[0][buf][s * 512];
        const unsigned short* g;
        if (buf == 0) {
            g = Xg + (size_t)(row0 + r) * H_ + c * 8;
        } else {
            int bn = n0 + r; if (bn > D_ - 1) bn = D_ - 1;   // dup tail, masked in epilogue
            g = (buf == 1 ? Bg : Bu) + (size_t)bn * H_ + c * 8;
        }
        gsrc[i] = g;
    }

    auto issue = [&](int k0, int set) {
#pragma unroll
        for (int i = 0; i < 6; ++i)
            gload_lds16(gsrc[i] + k0, lbase[i] + set * 12288);
    };
    auto compute = [&](int set) {
        const unsigned short* S = &lds[set][0][0];
        s16x8 af[4], bgf[4], buf2[4];
#pragma unroll
        for (int i = 0; i < 4; ++i) {
            int R = wm * 64 + i * 16 + ml;
            af[i] = *(const s16x8*)(S + R * 32 + sw);
        }
#pragma unroll
        for (int j = 0; j < 4; ++j) {
            int R = wn * 64 + j * 16 + ml;
            int o2 = R * 32 + sw;
            bgf[j]  = *(const s16x8*)(S + 4096 + o2);
            buf2[j] = *(const s16x8*)(S + 8192 + o2);
        }
#pragma unroll
        for (int i = 0; i < 4; ++i)
#pragma unroll
            for (int j = 0; j < 4; ++j) {
                accg[i][j] = __builtin_amdgcn_mfma_f32_16x16x32_bf16(af[i], bgf[j],  accg[i][j], 0, 0, 0);
                accu[i][j] = __builtin_amdgcn_mfma_f32_16x16x32_bf16(af[i], buf2[j], accu[i][j], 0, 0, 0);
            }
    };

    // single-barrier ping-pong: loads for step k+1 fly during step k's compute
    issue(0, 0);
    for (int k0 = 0; k0 < H_; k0 += 64) {
        __syncthreads();               // drains set-0 loads; set-1 reads of prev iter done
        issue(k0 + 32, 1);
        compute(0);
        __syncthreads();               // drains set-1 loads
        if (k0 + 64 < H_) issue(k0 + 64, 0);
        compute(1);
    }

    // epilogue: C/D layout col=lane&15, row=(lane>>4)*4+reg  [m89/m91]
    int mbase = row0 + wm * 64;
    int nbase = n0 + wn * 64;
#pragma unroll
    for (int i = 0; i < 4; ++i)
#pragma unroll
        for (int j = 0; j < 4; ++j) {
            int n = nbase + j * 16 + ml;
            if (n < D_) {
#pragma unroll
                for (int r = 0; r < 4; ++r) {
                    int m = mbase + i * 16 + q * 4 + r;
                    float g = accg[i][j][r], u = accu[i][j][r];
                    float hv = (g / (1.f + __expf(-g))) * u;   // silu(g)*u
                    hidden[(size_t)m * D_ + n] = __float2bfloat16(hv);
                }
            }
        }
}

// ---------------- GEMM2: eo[r] = hidden[r] * WdT^T  (bf16 out, unweighted) ----------------
__global__ __launch_bounds__(256, 2) void k_gemm2(
    const unsigned short* __restrict__ Hd,
    const unsigned short* __restrict__ WdT,
    const int* __restrict__ off,
    __hip_bfloat16* __restrict__ eo) {
    __shared__ unsigned short lds[2][2][4096];   // 2 sets x {A,B} x 8KB

    int row0 = blockIdx.y * 128;
    int off9[9];
#pragma unroll
    for (int i = 0; i < 9; ++i) off9[i] = off[i];
    int Mtot = off9[8] + T_;
    if (row0 >= Mtot) return;
    int e = 0;
#pragma unroll
    for (int i = 1; i < 9; ++i) e += (row0 >= off9[i]) ? 1 : 0;

    int n0 = blockIdx.x * 128;                      // N=1024, exact
    const unsigned short* Bd = WdT + (size_t)e * H_ * D_;

    int tid = threadIdx.x;
    int wave = tid >> 6, lane = tid & 63;
    int wm = wave >> 1, wn = wave & 1;
    int ml = lane & 15, q = lane >> 4;
    int sw = ((q + (ml >> 1)) & 3) * 8;

    f32x4 acc[4][4];
#pragma unroll
    for (int i = 0; i < 4; ++i)
#pragma unroll
        for (int j = 0; j < 4; ++j) acc[i][j] = (f32x4)0.f;

    const unsigned short* gsrc[4];
    unsigned short* lbase[4];
#pragma unroll
    for (int i = 0; i < 4; ++i) {
        int qq = wave * 4 + i;
        int buf = qq >> 3, s = qq & 7;
        int r = s * 16 + (lane >> 2);
        int c = ((lane & 3) - (r >> 1)) & 3;
        lbase[i] = &lds[0][buf][s * 512];
        gsrc[i] = (buf == 0)
            ? Hd + (size_t)(row0 + r) * D_ + c * 8
            : Bd + (size_t)(n0 + r) * D_ + c * 8;
    }

    auto issue = [&](int k0, int set) {
#pragma unroll
        for (int i = 0; i < 4; ++i)
            gload_lds16(gsrc[i] + k0, lbase[i] + set * 8192);
    };
    auto compute = [&](int set) {
        const unsigned short* S = &lds[set][0][0];
        s16x8 af[4], bf[4];
#pragma unroll
        for (int i = 0; i < 4; ++i) {
            int R = wm * 64 + i * 16 + ml;
            af[i] = *(const s16x8*)(S + R * 32 + sw);
        }
#pragma unroll
        for (int j = 0; j < 4; ++j) {
            int R = wn * 64 + j * 16 + ml;
            bf[j] = *(const s16x8*)(S + 4096 + R * 32 + sw);
        }
#pragma unroll
        for (int i = 0; i < 4; ++i)
#pragma unroll
            for (int j = 0; j < 4; ++j)
                acc[i][j] = __builtin_amdgcn_mfma_f32_16x16x32_bf16(af[i], bf[j], acc[i][j], 0, 0, 0);
    };

    issue(0, 0);
    for (int k0 = 0; k0 < D_; k0 += 64) {           // D_=2752 = 43*64
        __syncthreads();
        issue(k0 + 32, 1);
        compute(0);
        __syncthreads();
        if (k0 + 64 < D_) issue(k0 + 64, 0);
        compute(1);
    }

    int mbase = row0 + wm * 64;
    int nbase = n0 + wn * 64;
#pragma unroll
    for (int i = 0; i < 4; ++i)
#pragma unroll
        for (int r = 0; r < 4; ++r) {
            int m = mbase + i * 16 + q * 4 + r;
#pragma unroll
            for (int j = 0; j < 4; ++j) {
                int n = nbase + j * 16 + ml;
                eo[(size_t)m * H_ + n] = __float2bfloat16(acc[i][j][r]);
            }
        }
}

// ---------------- combine: out[t] = w0*eo[r0] + w1*eo[r1] + eo[rshared] ----------------
__global__ void k_combine(const unsigned short* __restrict__ eo, const int* __restrict__ tok2row,
                          const int* __restrict__ off, const float* __restrict__ topk_w,
                          float* __restrict__ out) {
    int t = blockIdx.x;
    int j = threadIdx.x * 8;                  // H = 128*8
    int r0 = tok2row[2 * t], r1 = tok2row[2 * t + 1];
    int rs = off[E_] + t;
    float w0 = topk_w[2 * t], w1 = topk_w[2 * t + 1];
    s16x8 a = *(const s16x8*)(eo + (size_t)r0 * H_ + j);
    s16x8 b = *(const s16x8*)(eo + (size_t)r1 * H_ + j);
    s16x8 c = *(const s16x8*)(eo + (size_t)rs * H_ + j);
    float o[8];
#pragma unroll
    for (int i = 0; i < 8; ++i)
        o[i] = w0 * bf2f(a[i]) + w1 * bf2f(b[i]) + bf2f(c[i]);
    float* dst = out + (size_t)t * H_ + j;
    *(float4*)(dst)     = make_float4(o[0], o[1], o[2], o[3]);
    *(float4*)(dst + 4) = make_float4(o[4], o[5], o[6], o[7]);
}

// ---------------- launch ----------------
extern "C" void kernel_launch(void* const* d_in, const int* in_sizes, int n_in,
                              void* d_out, int out_size, void* d_ws, size_t ws_size,
                              hipStream_t stream) {
    const float* x       = (const float*)d_in[0];
    const float* gw      = (const float*)d_in[1];
    const float* we_gate = (const float*)d_in[2];
    const float* we_up   = (const float*)d_in[3];
    const float* we_down = (const float*)d_in[4];
    const float* sw_gate = (const float*)d_in[5];
    const float* sw_up   = (const float*)d_in[6];
    const float* sw_down = (const float*)d_in[7];

    char* ws = (char*)d_ws;
    size_t o = 0;
    auto alloc = [&](size_t b) -> void* {
        void* p = ws + o;
        o += (b + 255) & ~(size_t)255;
        return p;
    };
    int*   count   = (int*)alloc(E_ * 4);
    int*   count2  = (int*)alloc(E_ * 4);
    int*   off     = (int*)alloc(16 * 4);
    int*   topk_e  = (int*)alloc(2 * T_ * 4);
    float* topk_w  = (float*)alloc(2 * T_ * 4);
    int*   perm    = (int*)alloc(MMAX_ * 4);
    float* wrow    = (float*)alloc(MMAX_ * 4);
    int*   tok2row = (int*)alloc(2 * T_ * 4);
    __hip_bfloat16* Xg  = (__hip_bfloat16*)alloc((size_t)MMAX_ * H_ * 2);
    __hip_bfloat16* WgT = (__hip_bfloat16*)alloc((size_t)(E_ + 1) * D_ * H_ * 2);
    __hip_bfloat16* WuT = (__hip_bfloat16*)alloc((size_t)(E_ + 1) * D_ * H_ * 2);
    __hip_bfloat16* WdT = (__hip_bfloat16*)alloc((size_t)(E_ + 1) * H_ * D_ * 2);
    __hip_bfloat16* hidden = (__hip_bfloat16*)alloc((size_t)MMAX_ * D_ * 2);
    // eo (bf16, 27 MB) aliases WgT (50 MB), dead after GEMM1
    __hip_bfloat16* eo = WgT;

    // routing
    k_init<<<(MMAX_ + 255) / 256, 256, 0, stream>>>(count, perm, wrow);
    k_gate<<<T_, 64, 0, stream>>>(x, gw, topk_e, topk_w, count);
    k_scan<<<1, 64, 0, stream>>>(count, off, count2);
    k_scatter<<<(3 * T_ + 255) / 256, 256, 0, stream>>>(topk_e, topk_w, off, count2,
                                                        perm, wrow, tok2row);
    k_gather<<<MMAX_, 128, 0, stream>>>(x, perm, wrow, Xg);

    // weight transpose+convert: experts in slots 0..7, shared in slot 8
    size_t msz = (size_t)D_ * H_;
    k_transpose<<<dim3(D_ / 64, H_ / 64, E_), 256, 0, stream>>>(we_gate, WgT, H_, D_);
    k_transpose<<<dim3(D_ / 64, H_ / 64, 1), 256, 0, stream>>>(sw_gate, WgT + E_ * msz, H_, D_);
    k_transpose<<<dim3(D_ / 64, H_ / 64, E_), 256, 0, stream>>>(we_up, WuT, H_, D_);
    k_transpose<<<dim3(D_ / 64, H_ / 64, 1), 256, 0, stream>>>(sw_up, WuT + E_ * msz, H_, D_);
    k_transpose<<<dim3(H_ / 64, D_ / 64, E_), 256, 0, stream>>>(we_down, WdT, D_, H_);
    k_transpose<<<dim3(H_ / 64, D_ / 64, 1), 256, 0, stream>>>(sw_down, WdT + E_ * msz, D_, H_);

    // GEMM1: fused gate+up+silu -> hidden (bf16)
    k_gemm1<<<dim3((D_ + 127) / 128, MTILES_), 256, 0, stream>>>(
        (const unsigned short*)Xg, (const unsigned short*)WgT, (const unsigned short*)WuT,
        hidden, off);

    // GEMM2: down-proj -> eo rows (bf16, unweighted)
    k_gemm2<<<dim3(H_ / 128, MTILES_), 256, 0, stream>>>(
        (const unsigned short*)hidden, (const unsigned short*)WdT, off, eo);

    // combine: weighted sum of the token's 3 rows
    k_combine<<<T_, 128, 0, stream>>>((const unsigned short*)eo, tok2row, off, topk_w,
                                      (float*)d_out);
}